// Round 7
// baseline (6711.629 us; speedup 1.0000x reference)
//
#include <hip/hip_runtime.h>
#include <hip/hip_bf16.h>
#include <math.h>

// Problem constants (B,S,E,H,T) = (32, 512, 300, 512, 9)
#define S_LEN 512
#define BATCH 32
#define HDIM  512
#define NTAG  9
#define M_ROWS (S_LEN * BATCH)      // 16384 rows, m = s*32 + b
#define GATES  4096                 // 2 dirs * 4 gates * 512

typedef __hip_bfloat16 bf16;
typedef unsigned long long ull;
typedef float f32x4 __attribute__((ext_vector_type(4)));
typedef float f32x16 __attribute__((ext_vector_type(16)));
typedef short bfrag8 __attribute__((ext_vector_type(8)));   // 8 bf16 = 4 VGPR

__device__ __forceinline__ float bf2f(short s) {
    unsigned u = ((unsigned)(unsigned short)s) << 16;
    return __builtin_bit_cast(float, u);
}
__device__ __forceinline__ short f2bf(float f) {
    __hip_bfloat16 h = __float2bfloat16(f);
    return __builtin_bit_cast(short, h);
}
// fast gate nonlinearities (validated absmax-0 rounds 4-6)
__device__ __forceinline__ float fsig(float x) {
    return __builtin_amdgcn_rcpf(1.f + __expf(-x));
}
__device__ __forceinline__ float ftanh(float x) {
    return 1.f - 2.f * __builtin_amdgcn_rcpf(1.f + __expf(2.f * x));
}

// ============================================================================
// MFMA GEMM: xg(M x 4096) = A(M x K) * Bw(4096 x K)^T + bias1[n] + bias2[n]
// (unchanged — verified absmax 0)
// ============================================================================
template <int AMODE>
__global__ __launch_bounds__(256) void gemm_xg(const void* __restrict__ Ap,
                                               const float* __restrict__ Bw,
                                               int K, int KT,
                                               const float* __restrict__ bias1,
                                               const float* __restrict__ bias2,
                                               short* __restrict__ xg) {
    __shared__ char smem[32768];
    char* As = smem;
    char* Bs = smem + 16384;
    const int tid = threadIdx.x;
    const int bm = blockIdx.y * 128;
    const int bn = blockIdx.x * 128;
    const int l  = tid & 63;
    const int wv = tid >> 6;
    const int wr = wv >> 1, wc = wv & 1;

    f32x4 acc[4][4] = {};

    const int r_st  = tid >> 1;
    const int kh    = tid & 1;
    const int xorr  = (r_st & 7) << 4;

    for (int kt = 0; kt < KT; kt++) {
        const int k0 = kt * 64;
        if (AMODE == 0) {
            const float* A = (const float*)Ap;
            int mg = bm + r_st;
            const float* arow = A + ((size_t)(mg & 31) * S_LEN + (mg >> 5)) * 300;
#pragma unroll
            for (int u = 0; u < 8; u++) {
                int kk = k0 + kh * 32 + u * 4;
                float4 v = make_float4(0.f, 0.f, 0.f, 0.f);
                if (kk + 4 <= K) v = *(const float4*)(arow + kk);
                short4 sv = make_short4(f2bf(v.x), f2bf(v.y), f2bf(v.z), f2bf(v.w));
                *(short4*)(As + ((r_st * 128 + (kh * 64 + u * 8)) ^ xorr)) = sv;
            }
        } else {
            const short* A = (const short*)Ap;
            const short* arow = A + (size_t)(bm + r_st) * 1024;
#pragma unroll
            for (int u = 0; u < 4; u++) {
                int kk = k0 + kh * 32 + u * 8;
                bfrag8 v = *(const bfrag8*)(arow + kk);
                *(bfrag8*)(As + ((r_st * 128 + (kh * 64 + u * 16)) ^ xorr)) = v;
            }
        }
        {
            const float* brow = Bw + (size_t)(bn + r_st) * K;
#pragma unroll
            for (int u = 0; u < 8; u++) {
                int kk = k0 + kh * 32 + u * 4;
                float4 v = make_float4(0.f, 0.f, 0.f, 0.f);
                if (kk + 4 <= K) v = *(const float4*)(brow + kk);
                short4 sv = make_short4(f2bf(v.x), f2bf(v.y), f2bf(v.z), f2bf(v.w));
                *(short4*)(Bs + ((r_st * 128 + (kh * 64 + u * 8)) ^ xorr)) = sv;
            }
        }
        __syncthreads();
#pragma unroll
        for (int kf = 0; kf < 2; kf++) {
            bfrag8 af[4], bfr[4];
#pragma unroll
            for (int ms = 0; ms < 4; ms++) {
                int row = wr * 64 + ms * 16 + (l & 15);
                af[ms] = *(const bfrag8*)(As + ((row * 128 + kf * 64 + (l >> 4) * 16) ^ ((row & 7) << 4)));
            }
#pragma unroll
            for (int ns = 0; ns < 4; ns++) {
                int row = wc * 64 + ns * 16 + (l & 15);
                bfr[ns] = *(const bfrag8*)(Bs + ((row * 128 + kf * 64 + (l >> 4) * 16) ^ ((row & 7) << 4)));
            }
#pragma unroll
            for (int ms = 0; ms < 4; ms++)
#pragma unroll
                for (int ns = 0; ns < 4; ns++)
                    acc[ms][ns] = __builtin_amdgcn_mfma_f32_16x16x32_bf16(af[ms], bfr[ns], acc[ms][ns], 0, 0, 0);
        }
        __syncthreads();
    }
#pragma unroll
    for (int ns = 0; ns < 4; ns++) {
        int n = bn + wc * 64 + ns * 16 + (l & 15);
        float bsum = bias1[n] + bias2[n];
#pragma unroll
        for (int ms = 0; ms < 4; ms++) {
#pragma unroll
            for (int r = 0; r < 4; r++) {
                int m = bm + wr * 64 + ms * 16 + (l >> 4) * 4 + r;
                xg[(size_t)m * GATES + n] = f2bf(acc[ms][ns][r] + bsum);
            }
        }
    }
}

// ============================================================================
// Persistent bidirectional LSTM scan, v5 = v4 seqlock protocol + k-split MFMA.
// 16 wgs x 512 thr. wg = dir*8 + p; wg owns j in [p*64, p*64+64), all 4 gates.
// Wave wv -> (g = wv&3, kh2 = wv>>2): 32x64 output tile over k-half kh2 (256 wide).
// Two independent 16-MFMA chains (acc0/acc1 = j-subtiles), one shared A-read.
// Partial sums exchanged via Cb[kh2][g][b][j] (padded 65); gate update adds halves.
// pub word (8B atomic): [tag:32 | 2x bf16]; poll until all 16 words tag==t.
// MFMA 32x32x16 maps (verified r3-r6): A row=l&31, k=(l>>5)*8+i; B col=l&31 same k;
// C col=l&31(n), b=(r&3)+8*(r>>2)+4*(l>>5).
// ============================================================================
__global__ __launch_bounds__(512, 1) void lstm_scan(const short* __restrict__ xg,
                                                    const float* __restrict__ whh,
                                                    ull* __restrict__ pub,     // 2 slots * 2 dirs * 8192 words
                                                    short* __restrict__ hseq) {
    const int wg  = blockIdx.x;
    const int dir = wg >> 3;
    const int p   = wg & 7;
    const int tid = threadIdx.x;
    const int wv  = tid >> 6;
    const int l   = tid & 63;
    const int g   = wv & 3;             // gate 0..3
    const int kh2 = wv >> 2;            // k-half 0/1 (256 wide)
    const int qh  = l >> 5;
    const int col = l & 31;

    __shared__ char hst[32768];         // h staged [32 b][1024 B], XOR-swizzled
    __shared__ float Cb[2][4][32][65];  // [khalf][gate][b][jloc] partial sums, padded

    // ---- recurrent weights -> registers (once): wf[jj2][ks] ----
    bfrag8 wf[2][16];
#pragma unroll
    for (int jj2 = 0; jj2 < 2; jj2++) {
        const float* sp = whh + ((size_t)dir * 2048 + g * 512 + p * 64 + jj2 * 32 + col) * 512
                        + kh2 * 256;
#pragma unroll
        for (int ks = 0; ks < 16; ks++) {
            const float* q = sp + ks * 16 + qh * 8;
            bfrag8 v;
#pragma unroll
            for (int u = 0; u < 8; u++) v[u] = f2bf(q[u]);
            wf[jj2][ks] = v;
        }
    }

    const int bg = tid >> 4;
    const int jq = tid & 15;
    float c4[4] = {0.f, 0.f, 0.f, 0.f};

    short4 xr_cur[4], xr_nxt[4];
    {
        const int s0 = dir ? (S_LEN - 1) : 0;
        size_t xoff = ((size_t)s0 * BATCH + bg) * GATES + dir * 2048 + p * 64 + jq * 4;
#pragma unroll
        for (int g2 = 0; g2 < 4; g2++) xr_cur[g2] = *(const short4*)(xg + xoff + g2 * 512);
    }

    for (int t = 0; t < S_LEN; t++) {
        const int s = dir ? (S_LEN - 1 - t) : t;
        // ---- prefetch xg for t+1 (hides under poll) ----
        {
            const int tn = (t + 1 < S_LEN) ? t + 1 : t;
            const int sn = dir ? (S_LEN - 1 - tn) : tn;
            size_t xoff = ((size_t)sn * BATCH + bg) * GATES + dir * 2048 + p * 64 + jq * 4;
#pragma unroll
            for (int g2 = 0; g2 < 4; g2++) xr_nxt[g2] = *(const short4*)(xg + xoff + g2 * 512);
        }
        // ---- poll-gather: my 16 words until all carry tag==t ----
        const ull* src = pub + (size_t)((t & 1) * 2 + dir) * 8192;
        const unsigned expect = (unsigned)t;
        ull wvv[16];
        {
            int rounds = 0;
            bool ok;
            do {
                if (rounds++) __builtin_amdgcn_s_sleep(1);
                ok = true;
#pragma unroll
                for (int i = 0; i < 16; i++) {
                    wvv[i] = __hip_atomic_load(src + tid + i * 512, __ATOMIC_RELAXED,
                                               __HIP_MEMORY_SCOPE_AGENT);
                    ok &= ((unsigned)(wvv[i] >> 32) == expect);
                }
                if (rounds > (1 << 14)) break;
            } while (!__all(ok));
        }
        // ---- unpack -> swizzled LDS ----
#pragma unroll
        for (int i = 0; i < 16; i++) {
            int w = tid + i * 512;
            int b = w >> 8, kp = w & 255;
            *(unsigned*)(hst + ((b * 1024 + kp * 4) ^ ((b & 15) << 4))) = (unsigned)wvv[i];
        }
        __syncthreads();
        // ---- MFMA: two independent 16-chains over k-half kh2 ----
        f32x16 acc0 = {}, acc1 = {};
#pragma unroll
        for (int ks = 0; ks < 16; ks++) {
            int byte = col * 1024 + kh2 * 512 + ks * 32 + qh * 16;
            const bfrag8 a = *(const bfrag8*)(hst + (byte ^ ((col & 15) << 4)));
            acc0 = __builtin_amdgcn_mfma_f32_32x32x16_bf16(a, wf[0][ks], acc0, 0, 0, 0);
            acc1 = __builtin_amdgcn_mfma_f32_32x32x16_bf16(a, wf[1][ks], acc1, 0, 0, 0);
        }
        // ---- partial-C exchange ----
#pragma unroll
        for (int r = 0; r < 16; r++) {
            int brow = (r & 3) + 8 * (r >> 2) + 4 * qh;
            Cb[kh2][g][brow][col]      = acc0[r];
            Cb[kh2][g][brow][32 + col] = acc1[r];
        }
        __syncthreads();
        // ---- gates / state update (sum the two k-halves) ----
        float hv[4];
        {
            float xi[4] = {bf2f(xr_cur[0].x), bf2f(xr_cur[0].y), bf2f(xr_cur[0].z), bf2f(xr_cur[0].w)};
            float xf[4] = {bf2f(xr_cur[1].x), bf2f(xr_cur[1].y), bf2f(xr_cur[1].z), bf2f(xr_cur[1].w)};
            float xc[4] = {bf2f(xr_cur[2].x), bf2f(xr_cur[2].y), bf2f(xr_cur[2].z), bf2f(xr_cur[2].w)};
            float xo[4] = {bf2f(xr_cur[3].x), bf2f(xr_cur[3].y), bf2f(xr_cur[3].z), bf2f(xr_cur[3].w)};
#pragma unroll
            for (int q = 0; q < 4; q++) {
                int jl = jq * 4 + q;
                float gi = Cb[0][0][bg][jl] + Cb[1][0][bg][jl] + xi[q];
                float gf = Cb[0][1][bg][jl] + Cb[1][1][bg][jl] + xf[q];
                float gc = Cb[0][2][bg][jl] + Cb[1][2][bg][jl] + xc[q];
                float go = Cb[0][3][bg][jl] + Cb[1][3][bg][jl] + xo[q];
                float cc = fsig(gf) * c4[q] + fsig(gi) * ftanh(gc);
                c4[q] = cc;
                hv[q] = fsig(go) * ftanh(cc);
            }
        }
        // ---- publish h[t+1] as tagged words + hseq store (fire-and-forget) ----
        {
            unsigned short h0 = (unsigned short)f2bf(hv[0]);
            unsigned short h1 = (unsigned short)f2bf(hv[1]);
            unsigned short h2 = (unsigned short)f2bf(hv[2]);
            unsigned short h3 = (unsigned short)f2bf(hv[3]);
            ull tagw = (ull)(unsigned)(t + 1) << 32;
            ull w0 = tagw | (ull)h0 | ((ull)h1 << 16);
            ull w1 = tagw | (ull)h2 | ((ull)h3 << 16);
            ull* dst = pub + (size_t)(((t + 1) & 1) * 2 + dir) * 8192 + bg * 256 + p * 32 + jq * 2;
            __hip_atomic_store(dst, w0, __ATOMIC_RELAXED, __HIP_MEMORY_SCOPE_AGENT);
            __hip_atomic_store(dst + 1, w1, __ATOMIC_RELAXED, __HIP_MEMORY_SCOPE_AGENT);
            ull pk = (ull)h0 | ((ull)h1 << 16) | ((ull)h2 << 32) | ((ull)h3 << 48);
            ull* hd = (ull*)(hseq + ((size_t)s * BATCH + bg) * 1024 + dir * HDIM + p * 64 + jq * 4);
            __builtin_nontemporal_store(pk, hd);
        }
#pragma unroll
        for (int g2 = 0; g2 < 4; g2++) xr_cur[g2] = xr_nxt[g2];
    }
}

// ---- emissions (B,S,T) = h1 (M_ROWS,1024) bf16 @ proj_w(9,1024)^T + proj_b ----
__global__ __launch_bounds__(256) void proj_kernel(const bf16* __restrict__ h1,
                                                   const float* __restrict__ pw,
                                                   const float* __restrict__ pb,
                                                   float* __restrict__ em) {
    __shared__ float wl[NTAG * 1024];
    __shared__ float bl[NTAG];
    for (int i = threadIdx.x; i < NTAG * 1024; i += 256) wl[i] = pw[i];
    if (threadIdx.x < NTAG) bl[threadIdx.x] = pb[threadIdx.x];
    __syncthreads();
    int m = blockIdx.x * 256 + threadIdx.x;
    int s = m >> 5, b = m & 31;
    const bf16* hr = h1 + (size_t)m * 1024;
    float acc[NTAG] = {};
    for (int k = 0; k < 1024; k += 8) {
        uint4 raw = *(const uint4*)(hr + k);
        const bf16* hv = (const bf16*)&raw;
        float hf[8];
#pragma unroll
        for (int u = 0; u < 8; u++) hf[u] = __bfloat162float(hv[u]);
#pragma unroll
        for (int tt = 0; tt < NTAG; tt++) {
            const float* wrow = &wl[tt * 1024 + k];
#pragma unroll
            for (int u = 0; u < 8; u++) acc[tt] += hf[u] * wrow[u];
        }
    }
#pragma unroll
    for (int tt = 0; tt < NTAG; tt++)
        em[((size_t)b * S_LEN + s) * NTAG + tt] = acc[tt] + bl[tt];
}

// ---- CRF NLL per batch element ----
__global__ __launch_bounds__(64) void crf_kernel(const float* __restrict__ em,
                                                 const int* __restrict__ tags,
                                                 const int* __restrict__ mask,
                                                 const float* __restrict__ trans,
                                                 const float* __restrict__ startv,
                                                 const float* __restrict__ endv,
                                                 float* __restrict__ out_b) {
    int b = blockIdx.x;
    int lane = threadIdx.x;
    const float* E = em + (size_t)b * S_LEN * NTAG;
    const int* tg = tags + (size_t)b * S_LEN;
    const int* mk = mask + (size_t)b * S_LEN;

    float np = 0.f;
    int msum = 0;
    for (int s = lane; s < S_LEN; s += 64) {
        msum += (mk[s] != 0);
        if (s >= 1) {
            float mf = (float)mk[s];
            int ts = tg[s], tp = tg[s - 1];
            np += (E[(size_t)s * NTAG + ts] + trans[tp * NTAG + ts]) * mf;
        }
    }
    for (int off = 32; off; off >>= 1) {
        np += __shfl_down(np, off);
        msum += __shfl_down(msum, off);
    }
    np = __shfl(np, 0);
    msum = __shfl(msum, 0);

    int j = lane;
    float tcol[NTAG];
    if (j < NTAG)
#pragma unroll
        for (int i = 0; i < NTAG; i++) tcol[i] = trans[i * NTAG + j];
    float alpha = (j < NTAG) ? (startv[j] + E[j]) : -1e30f;
    for (int s = 1; s < S_LEN; s++) {
        float av[NTAG];
#pragma unroll
        for (int i = 0; i < NTAG; i++) av[i] = __shfl(alpha, i);
        if (j < NTAG) {
            float m = -1e30f;
#pragma unroll
            for (int i = 0; i < NTAG; i++) m = fmaxf(m, av[i] + tcol[i]);
            float ss = 0.f;
#pragma unroll
            for (int i = 0; i < NTAG; i++) ss += __expf(av[i] + tcol[i] - m);
            float nxt = m + __logf(ss) + E[(size_t)s * NTAG + j];
            if (mk[s] != 0) alpha = nxt;
        }
    }
    float val = (j < NTAG) ? (alpha + endv[j]) : -1e30f;
    float m2 = -1e30f, vv;
#pragma unroll
    for (int i = 0; i < NTAG; i++) { vv = __shfl(val, i); m2 = fmaxf(m2, vv); }
    float s2 = 0.f;
#pragma unroll
    for (int i = 0; i < NTAG; i++) { vv = __shfl(val, i); s2 += __expf(vv - m2); }
    float denom = m2 + __logf(s2);
    if (lane == 0) {
        int t0 = tg[0];
        int last = msum - 1;
        if (last < 0) last = 0;
        int lt = tg[last];
        float num = startv[t0] + E[t0] + np + endv[lt];
        out_b[b] = num - denom;
    }
}

__global__ __launch_bounds__(64) void finalize(const float* __restrict__ out_b,
                                               float* __restrict__ out) {
    int lane = threadIdx.x;
    float v = (lane < BATCH) ? out_b[lane] : 0.f;
    for (int off = 32; off; off >>= 1) v += __shfl_down(v, off);
    if (lane == 0) out[0] = -v / (float)BATCH;
}

extern "C" void kernel_launch(void* const* d_in, const int* in_sizes, int n_in,
                              void* d_out, int out_size, void* d_ws, size_t ws_size,
                              hipStream_t stream) {
    const float* x      = (const float*)d_in[0];
    const int*   tags   = (const int*)d_in[1];
    const int*   mask   = (const int*)d_in[2];
    const float* w_ih0  = (const float*)d_in[3];   // (2,2048,300)
    const float* w_hh0  = (const float*)d_in[4];   // (2,2048,512)
    const float* b_ih0  = (const float*)d_in[5];
    const float* b_hh0  = (const float*)d_in[6];
    const float* w_ih1  = (const float*)d_in[7];   // (2,2048,1024)
    const float* w_hh1  = (const float*)d_in[8];
    const float* b_ih1  = (const float*)d_in[9];
    const float* b_hh1  = (const float*)d_in[10];
    const float* pw     = (const float*)d_in[11];
    const float* pb     = (const float*)d_in[12];
    const float* trans  = (const float*)d_in[13];
    const float* startv = (const float*)d_in[14];
    const float* endv   = (const float*)d_in[15];

    // ---- ws layout (bytes). Total ~168.6 MB. ----
    char* ws = (char*)d_ws;
    size_t off = 0;
    short* xg    = (short*)(ws + off); off += (size_t)M_ROWS * GATES * 2;   // 134,217,728
    short* hseq  = (short*)(ws + off); off += (size_t)M_ROWS * 1024 * 2;    //  33,554,432
    ull*   pub   = (ull*)(ws + off);   off += (size_t)2 * 2 * 8192 * 8;     //     262,144
    float* emis  = (float*)(ws + off); off += (size_t)BATCH * S_LEN * NTAG * 4; // 589,824
    float* outb  = (float*)(ws + off); off += 256;
    if (off > ws_size) return;

    const size_t pub_bytes = (size_t)2 * 2 * 8192 * 8;

    // ---- layer 0 ----
    gemm_xg<0><<<dim3(32, 128), 256, 0, stream>>>(x, w_ih0, 300, 5, b_ih0, b_hh0, xg);
    hipMemsetAsync(pub, 0, pub_bytes, stream);
    lstm_scan<<<16, 512, 0, stream>>>(xg, w_hh0, pub, hseq);

    // ---- layer 1 ----
    gemm_xg<1><<<dim3(32, 128), 256, 0, stream>>>(hseq, w_ih1, 1024, 16, b_ih1, b_hh1, xg);
    hipMemsetAsync(pub, 0, pub_bytes, stream);
    lstm_scan<<<16, 512, 0, stream>>>(xg, w_hh1, pub, hseq);

    // ---- projection + CRF ----
    proj_kernel<<<M_ROWS / 256, 256, 0, stream>>>((const bf16*)hseq, pw, pb, emis);
    crf_kernel<<<BATCH, 64, 0, stream>>>(emis, tags, mask, trans, startv, endv, outb);
    finalize<<<1, 64, 0, stream>>>(outb, (float*)d_out);
}

// Round 8
// 6565.197 us; speedup vs baseline: 1.0223x; 1.0223x over previous
//
#include <hip/hip_runtime.h>
#include <hip/hip_bf16.h>
#include <math.h>

// Problem constants (B,S,E,H,T) = (32, 512, 300, 512, 9)
#define S_LEN 512
#define BATCH 32
#define HDIM  512
#define NTAG  9
#define M_ROWS (S_LEN * BATCH)      // 16384 rows, m = s*32 + b
#define GATES  4096                 // 2 dirs * 4 gates * 512
#define NSCAN_WG 16
#define NHEAT_WG 240

typedef __hip_bfloat16 bf16;
typedef unsigned long long ull;
typedef float f32x4 __attribute__((ext_vector_type(4)));
typedef float f32x16 __attribute__((ext_vector_type(16)));
typedef short bfrag8 __attribute__((ext_vector_type(8)));   // 8 bf16 = 4 VGPR

__device__ __forceinline__ float bf2f(short s) {
    unsigned u = ((unsigned)(unsigned short)s) << 16;
    return __builtin_bit_cast(float, u);
}
__device__ __forceinline__ short f2bf(float f) {
    __hip_bfloat16 h = __float2bfloat16(f);
    return __builtin_bit_cast(short, h);
}
// fast gate nonlinearities (validated absmax-0 rounds 4-7)
__device__ __forceinline__ float fsig(float x) {
    return __builtin_amdgcn_rcpf(1.f + __expf(-x));
}
__device__ __forceinline__ float ftanh(float x) {
    return 1.f - 2.f * __builtin_amdgcn_rcpf(1.f + __expf(2.f * x));
}

// ============================================================================
// MFMA GEMM: xg(M x 4096) = A(M x K) * Bw(4096 x K)^T + bias1[n] + bias2[n]
// (unchanged — verified absmax 0)
// ============================================================================
template <int AMODE>
__global__ __launch_bounds__(256) void gemm_xg(const void* __restrict__ Ap,
                                               const float* __restrict__ Bw,
                                               int K, int KT,
                                               const float* __restrict__ bias1,
                                               const float* __restrict__ bias2,
                                               short* __restrict__ xg) {
    __shared__ char smem[32768];
    char* As = smem;
    char* Bs = smem + 16384;
    const int tid = threadIdx.x;
    const int bm = blockIdx.y * 128;
    const int bn = blockIdx.x * 128;
    const int l  = tid & 63;
    const int wv = tid >> 6;
    const int wr = wv >> 1, wc = wv & 1;

    f32x4 acc[4][4] = {};

    const int r_st  = tid >> 1;
    const int kh    = tid & 1;
    const int xorr  = (r_st & 7) << 4;

    for (int kt = 0; kt < KT; kt++) {
        const int k0 = kt * 64;
        if (AMODE == 0) {
            const float* A = (const float*)Ap;
            int mg = bm + r_st;
            const float* arow = A + ((size_t)(mg & 31) * S_LEN + (mg >> 5)) * 300;
#pragma unroll
            for (int u = 0; u < 8; u++) {
                int kk = k0 + kh * 32 + u * 4;
                float4 v = make_float4(0.f, 0.f, 0.f, 0.f);
                if (kk + 4 <= K) v = *(const float4*)(arow + kk);
                short4 sv = make_short4(f2bf(v.x), f2bf(v.y), f2bf(v.z), f2bf(v.w));
                *(short4*)(As + ((r_st * 128 + (kh * 64 + u * 8)) ^ xorr)) = sv;
            }
        } else {
            const short* A = (const short*)Ap;
            const short* arow = A + (size_t)(bm + r_st) * 1024;
#pragma unroll
            for (int u = 0; u < 4; u++) {
                int kk = k0 + kh * 32 + u * 8;
                bfrag8 v = *(const bfrag8*)(arow + kk);
                *(bfrag8*)(As + ((r_st * 128 + (kh * 64 + u * 16)) ^ xorr)) = v;
            }
        }
        {
            const float* brow = Bw + (size_t)(bn + r_st) * K;
#pragma unroll
            for (int u = 0; u < 8; u++) {
                int kk = k0 + kh * 32 + u * 4;
                float4 v = make_float4(0.f, 0.f, 0.f, 0.f);
                if (kk + 4 <= K) v = *(const float4*)(brow + kk);
                short4 sv = make_short4(f2bf(v.x), f2bf(v.y), f2bf(v.z), f2bf(v.w));
                *(short4*)(Bs + ((r_st * 128 + (kh * 64 + u * 8)) ^ xorr)) = sv;
            }
        }
        __syncthreads();
#pragma unroll
        for (int kf = 0; kf < 2; kf++) {
            bfrag8 af[4], bfr[4];
#pragma unroll
            for (int ms = 0; ms < 4; ms++) {
                int row = wr * 64 + ms * 16 + (l & 15);
                af[ms] = *(const bfrag8*)(As + ((row * 128 + kf * 64 + (l >> 4) * 16) ^ ((row & 7) << 4)));
            }
#pragma unroll
            for (int ns = 0; ns < 4; ns++) {
                int row = wc * 64 + ns * 16 + (l & 15);
                bfr[ns] = *(const bfrag8*)(Bs + ((row * 128 + kf * 64 + (l >> 4) * 16) ^ ((row & 7) << 4)));
            }
#pragma unroll
            for (int ms = 0; ms < 4; ms++)
#pragma unroll
                for (int ns = 0; ns < 4; ns++)
                    acc[ms][ns] = __builtin_amdgcn_mfma_f32_16x16x32_bf16(af[ms], bfr[ns], acc[ms][ns], 0, 0, 0);
        }
        __syncthreads();
    }
#pragma unroll
    for (int ns = 0; ns < 4; ns++) {
        int n = bn + wc * 64 + ns * 16 + (l & 15);
        float bsum = bias1[n] + bias2[n];
#pragma unroll
        for (int ms = 0; ms < 4; ms++) {
#pragma unroll
            for (int r = 0; r < 4; r++) {
                int m = bm + wr * 64 + ms * 16 + (l >> 4) * 4 + r;
                xg[(size_t)m * GATES + n] = f2bf(acc[ms][ns][r] + bsum);
            }
        }
    }
}

// ============================================================================
// Persistent bidirectional LSTM scan, v6 = r6's verified v4 structure + heater.
// Blocks 0..15: scan (byte-identical to r6). Blocks 16..255: register-only FMA
// heater to hold clocks up; exits when done-counter==16 (or iteration cap).
// pub word (8B atomic): [tag:32 | 2x bf16]; poll until all 16 words tag==t.
// MFMA 32x32x16 maps (verified r3-r7): A row=l&31, k=(l>>5)*8+i; B col=l&31 same k;
// C col=l&31(n), b=(r&3)+8*(r>>2)+4*(l>>5).
// ============================================================================
__global__ __launch_bounds__(512, 1) void lstm_scan(const short* __restrict__ xg,
                                                    const float* __restrict__ whh,
                                                    ull* __restrict__ pub,     // 2 slots * 2 dirs * 8192 words (+done)
                                                    short* __restrict__ hseq,
                                                    int* __restrict__ done) {
    const int wg  = blockIdx.x;
    const int tid = threadIdx.x;

    if (wg >= NSCAN_WG) {
        // ---- heater: register-only FMA spin; no LDS, no memory traffic except
        // a done-poll every 256 iters. Bounded: never hangs. ----
        float r0 = (float)tid * 0.001f + 1.f, r1 = r0 + 0.1f, r2 = r0 + 0.2f, r3 = r0 + 0.3f;
        float r4 = r0 + 0.4f, r5 = r0 + 0.5f, r6 = r0 + 0.6f, r7 = r0 + 0.7f;
        const float a = 1.0000001f, b = 1e-7f;
        for (int it = 0; it < (1 << 20); ++it) {
#pragma unroll
            for (int u = 0; u < 8; u++) {
                r0 = fmaf(r0, a, b); r1 = fmaf(r1, a, b);
                r2 = fmaf(r2, a, b); r3 = fmaf(r3, a, b);
                r4 = fmaf(r4, a, b); r5 = fmaf(r5, a, b);
                r6 = fmaf(r6, a, b); r7 = fmaf(r7, a, b);
            }
            if ((it & 255) == 0) {
                if (__hip_atomic_load(done, __ATOMIC_RELAXED, __HIP_MEMORY_SCOPE_AGENT) >= NSCAN_WG)
                    break;
            }
        }
        asm volatile("" :: "v"(r0), "v"(r1), "v"(r2), "v"(r3),
                           "v"(r4), "v"(r5), "v"(r6), "v"(r7));
        return;
    }

    const int dir = wg >> 3;
    const int p   = wg & 7;
    const int wv  = tid >> 6;
    const int l   = tid & 63;
    const int g   = wv >> 1;            // gate 0..3
    const int jb  = (wv & 1) * 32;      // j subtile within wg
    const int qh  = l >> 5;
    const int col = l & 31;

    __shared__ char hst[32768];         // h staged [32 b][1024 B], XOR-swizzled
    __shared__ float Cb[4][32][64];     // gate exchange

    // ---- recurrent weights -> registers (once) ----
    bfrag8 wf[32];
    {
        const int n_row = g * 512 + p * 64 + jb + col;
        const float* sp = whh + ((size_t)dir * 2048 + n_row) * 512;
#pragma unroll
        for (int ks = 0; ks < 32; ks++) {
            const float* q = sp + ks * 16 + qh * 8;
            bfrag8 v;
#pragma unroll
            for (int u = 0; u < 8; u++) v[u] = f2bf(q[u]);
            wf[ks] = v;
        }
    }

    const int bg = tid >> 4;
    const int jq = tid & 15;
    float c4[4] = {0.f, 0.f, 0.f, 0.f};

    short4 xr_cur[4], xr_nxt[4];
    {
        const int s0 = dir ? (S_LEN - 1) : 0;
        size_t xoff = ((size_t)s0 * BATCH + bg) * GATES + dir * 2048 + p * 64 + jq * 4;
#pragma unroll
        for (int g2 = 0; g2 < 4; g2++) xr_cur[g2] = *(const short4*)(xg + xoff + g2 * 512);
    }

    for (int t = 0; t < S_LEN; t++) {
        const int s = dir ? (S_LEN - 1 - t) : t;
        // ---- prefetch xg for t+1 (hides under poll) ----
        {
            const int tn = (t + 1 < S_LEN) ? t + 1 : t;
            const int sn = dir ? (S_LEN - 1 - tn) : tn;
            size_t xoff = ((size_t)sn * BATCH + bg) * GATES + dir * 2048 + p * 64 + jq * 4;
#pragma unroll
            for (int g2 = 0; g2 < 4; g2++) xr_nxt[g2] = *(const short4*)(xg + xoff + g2 * 512);
        }
        // ---- poll-gather: my 16 words until all carry tag==t ----
        const ull* src = pub + (size_t)((t & 1) * 2 + dir) * 8192;
        const unsigned expect = (unsigned)t;
        ull wvv[16];
        {
            int rounds = 0;
            bool ok;
            do {
                if (rounds++) __builtin_amdgcn_s_sleep(1);
                ok = true;
#pragma unroll
                for (int i = 0; i < 16; i++) {
                    wvv[i] = __hip_atomic_load(src + tid + i * 512, __ATOMIC_RELAXED,
                                               __HIP_MEMORY_SCOPE_AGENT);
                    ok &= ((unsigned)(wvv[i] >> 32) == expect);
                }
                if (rounds > (1 << 14)) break;
            } while (!__all(ok));
        }
        // ---- unpack -> swizzled LDS ----
#pragma unroll
        for (int i = 0; i < 16; i++) {
            int w = tid + i * 512;
            int b = w >> 8, kp = w & 255;
            *(unsigned*)(hst + ((b * 1024 + kp * 4) ^ ((b & 15) << 4))) = (unsigned)wvv[i];
        }
        __syncthreads();
        // ---- MFMA: C(32b x 32n) = h(32x512) * W^T ----
        f32x16 acc = {};
#pragma unroll
        for (int ks = 0; ks < 32; ks++) {
            int byte = col * 1024 + ks * 32 + qh * 16;
            const bfrag8 a = *(const bfrag8*)(hst + (byte ^ ((col & 15) << 4)));
            acc = __builtin_amdgcn_mfma_f32_32x32x16_bf16(a, wf[ks], acc, 0, 0, 0);
        }
        // ---- C exchange ----
#pragma unroll
        for (int r = 0; r < 16; r++) {
            int brow = (r & 3) + 8 * (r >> 2) + 4 * qh;
            Cb[g][brow][jb + col] = acc[r];
        }
        __syncthreads();
        // ---- gates / state update ----
        float hv[4];
        {
            float xi[4] = {bf2f(xr_cur[0].x), bf2f(xr_cur[0].y), bf2f(xr_cur[0].z), bf2f(xr_cur[0].w)};
            float xf[4] = {bf2f(xr_cur[1].x), bf2f(xr_cur[1].y), bf2f(xr_cur[1].z), bf2f(xr_cur[1].w)};
            float xc[4] = {bf2f(xr_cur[2].x), bf2f(xr_cur[2].y), bf2f(xr_cur[2].z), bf2f(xr_cur[2].w)};
            float xo[4] = {bf2f(xr_cur[3].x), bf2f(xr_cur[3].y), bf2f(xr_cur[3].z), bf2f(xr_cur[3].w)};
#pragma unroll
            for (int q = 0; q < 4; q++) {
                int jl = jq * 4 + q;
                float gi = Cb[0][bg][jl] + xi[q];
                float gf = Cb[1][bg][jl] + xf[q];
                float gc = Cb[2][bg][jl] + xc[q];
                float go = Cb[3][bg][jl] + xo[q];
                float cc = fsig(gf) * c4[q] + fsig(gi) * ftanh(gc);
                c4[q] = cc;
                hv[q] = fsig(go) * ftanh(cc);
            }
        }
        // ---- publish h[t+1] as tagged words + hseq store (fire-and-forget) ----
        {
            unsigned short h0 = (unsigned short)f2bf(hv[0]);
            unsigned short h1 = (unsigned short)f2bf(hv[1]);
            unsigned short h2 = (unsigned short)f2bf(hv[2]);
            unsigned short h3 = (unsigned short)f2bf(hv[3]);
            ull tagw = (ull)(unsigned)(t + 1) << 32;
            ull w0 = tagw | (ull)h0 | ((ull)h1 << 16);
            ull w1 = tagw | (ull)h2 | ((ull)h3 << 16);
            ull* dst = pub + (size_t)(((t + 1) & 1) * 2 + dir) * 8192 + bg * 256 + p * 32 + jq * 2;
            __hip_atomic_store(dst, w0, __ATOMIC_RELAXED, __HIP_MEMORY_SCOPE_AGENT);
            __hip_atomic_store(dst + 1, w1, __ATOMIC_RELAXED, __HIP_MEMORY_SCOPE_AGENT);
            ull pk = (ull)h0 | ((ull)h1 << 16) | ((ull)h2 << 32) | ((ull)h3 << 48);
            ull* hd = (ull*)(hseq + ((size_t)s * BATCH + bg) * 1024 + dir * HDIM + p * 64 + jq * 4);
            __builtin_nontemporal_store(pk, hd);
        }
#pragma unroll
        for (int g2 = 0; g2 < 4; g2++) xr_cur[g2] = xr_nxt[g2];
    }
    if (tid == 0)
        __hip_atomic_fetch_add(done, 1, __ATOMIC_RELAXED, __HIP_MEMORY_SCOPE_AGENT);
}

// ---- emissions (B,S,T) = h1 (M_ROWS,1024) bf16 @ proj_w(9,1024)^T + proj_b ----
__global__ __launch_bounds__(256) void proj_kernel(const bf16* __restrict__ h1,
                                                   const float* __restrict__ pw,
                                                   const float* __restrict__ pb,
                                                   float* __restrict__ em) {
    __shared__ float wl[NTAG * 1024];
    __shared__ float bl[NTAG];
    for (int i = threadIdx.x; i < NTAG * 1024; i += 256) wl[i] = pw[i];
    if (threadIdx.x < NTAG) bl[threadIdx.x] = pb[threadIdx.x];
    __syncthreads();
    int m = blockIdx.x * 256 + threadIdx.x;
    int s = m >> 5, b = m & 31;
    const bf16* hr = h1 + (size_t)m * 1024;
    float acc[NTAG] = {};
    for (int k = 0; k < 1024; k += 8) {
        uint4 raw = *(const uint4*)(hr + k);
        const bf16* hv = (const bf16*)&raw;
        float hf[8];
#pragma unroll
        for (int u = 0; u < 8; u++) hf[u] = __bfloat162float(hv[u]);
#pragma unroll
        for (int tt = 0; tt < NTAG; tt++) {
            const float* wrow = &wl[tt * 1024 + k];
#pragma unroll
            for (int u = 0; u < 8; u++) acc[tt] += hf[u] * wrow[u];
        }
    }
#pragma unroll
    for (int tt = 0; tt < NTAG; tt++)
        em[((size_t)b * S_LEN + s) * NTAG + tt] = acc[tt] + bl[tt];
}

// ---- CRF NLL per batch element ----
__global__ __launch_bounds__(64) void crf_kernel(const float* __restrict__ em,
                                                 const int* __restrict__ tags,
                                                 const int* __restrict__ mask,
                                                 const float* __restrict__ trans,
                                                 const float* __restrict__ startv,
                                                 const float* __restrict__ endv,
                                                 float* __restrict__ out_b) {
    int b = blockIdx.x;
    int lane = threadIdx.x;
    const float* E = em + (size_t)b * S_LEN * NTAG;
    const int* tg = tags + (size_t)b * S_LEN;
    const int* mk = mask + (size_t)b * S_LEN;

    float np = 0.f;
    int msum = 0;
    for (int s = lane; s < S_LEN; s += 64) {
        msum += (mk[s] != 0);
        if (s >= 1) {
            float mf = (float)mk[s];
            int ts = tg[s], tp = tg[s - 1];
            np += (E[(size_t)s * NTAG + ts] + trans[tp * NTAG + ts]) * mf;
        }
    }
    for (int off = 32; off; off >>= 1) {
        np += __shfl_down(np, off);
        msum += __shfl_down(msum, off);
    }
    np = __shfl(np, 0);
    msum = __shfl(msum, 0);

    int j = lane;
    float tcol[NTAG];
    if (j < NTAG)
#pragma unroll
        for (int i = 0; i < NTAG; i++) tcol[i] = trans[i * NTAG + j];
    float alpha = (j < NTAG) ? (startv[j] + E[j]) : -1e30f;
    for (int s = 1; s < S_LEN; s++) {
        float av[NTAG];
#pragma unroll
        for (int i = 0; i < NTAG; i++) av[i] = __shfl(alpha, i);
        if (j < NTAG) {
            float m = -1e30f;
#pragma unroll
            for (int i = 0; i < NTAG; i++) m = fmaxf(m, av[i] + tcol[i]);
            float ss = 0.f;
#pragma unroll
            for (int i = 0; i < NTAG; i++) ss += __expf(av[i] + tcol[i] - m);
            float nxt = m + __logf(ss) + E[(size_t)s * NTAG + j];
            if (mk[s] != 0) alpha = nxt;
        }
    }
    float val = (j < NTAG) ? (alpha + endv[j]) : -1e30f;
    float m2 = -1e30f, vv;
#pragma unroll
    for (int i = 0; i < NTAG; i++) { vv = __shfl(val, i); m2 = fmaxf(m2, vv); }
    float s2 = 0.f;
#pragma unroll
    for (int i = 0; i < NTAG; i++) { vv = __shfl(val, i); s2 += __expf(vv - m2); }
    float denom = m2 + __logf(s2);
    if (lane == 0) {
        int t0 = tg[0];
        int last = msum - 1;
        if (last < 0) last = 0;
        int lt = tg[last];
        float num = startv[t0] + E[t0] + np + endv[lt];
        out_b[b] = num - denom;
    }
}

__global__ __launch_bounds__(64) void finalize(const float* __restrict__ out_b,
                                               float* __restrict__ out) {
    int lane = threadIdx.x;
    float v = (lane < BATCH) ? out_b[lane] : 0.f;
    for (int off = 32; off; off >>= 1) v += __shfl_down(v, off);
    if (lane == 0) out[0] = -v / (float)BATCH;
}

extern "C" void kernel_launch(void* const* d_in, const int* in_sizes, int n_in,
                              void* d_out, int out_size, void* d_ws, size_t ws_size,
                              hipStream_t stream) {
    const float* x      = (const float*)d_in[0];
    const int*   tags   = (const int*)d_in[1];
    const int*   mask   = (const int*)d_in[2];
    const float* w_ih0  = (const float*)d_in[3];   // (2,2048,300)
    const float* w_hh0  = (const float*)d_in[4];   // (2,2048,512)
    const float* b_ih0  = (const float*)d_in[5];
    const float* b_hh0  = (const float*)d_in[6];
    const float* w_ih1  = (const float*)d_in[7];   // (2,2048,1024)
    const float* w_hh1  = (const float*)d_in[8];
    const float* b_ih1  = (const float*)d_in[9];
    const float* b_hh1  = (const float*)d_in[10];
    const float* pw     = (const float*)d_in[11];
    const float* pb     = (const float*)d_in[12];
    const float* trans  = (const float*)d_in[13];
    const float* startv = (const float*)d_in[14];
    const float* endv   = (const float*)d_in[15];

    // ---- ws layout (bytes). Total ~168.6 MB. ----
    char* ws = (char*)d_ws;
    size_t off = 0;
    short* xg    = (short*)(ws + off); off += (size_t)M_ROWS * GATES * 2;   // 134,217,728
    short* hseq  = (short*)(ws + off); off += (size_t)M_ROWS * 1024 * 2;    //  33,554,432
    ull*   pub   = (ull*)(ws + off);   off += (size_t)2 * 2 * 8192 * 8 + 256; // 262,400 (incl. done)
    float* emis  = (float*)(ws + off); off += (size_t)BATCH * S_LEN * NTAG * 4; // 589,824
    float* outb  = (float*)(ws + off); off += 256;
    if (off > ws_size) return;

    int* done = (int*)(pub + (size_t)2 * 2 * 8192);
    const size_t pub_bytes = (size_t)2 * 2 * 8192 * 8 + 256;  // pub + done, one memset

    // ---- layer 0 ----
    gemm_xg<0><<<dim3(32, 128), 256, 0, stream>>>(x, w_ih0, 300, 5, b_ih0, b_hh0, xg);
    hipMemsetAsync(pub, 0, pub_bytes, stream);
    lstm_scan<<<NSCAN_WG + NHEAT_WG, 512, 0, stream>>>(xg, w_hh0, pub, hseq, done);

    // ---- layer 1 ----
    gemm_xg<1><<<dim3(32, 128), 256, 0, stream>>>(hseq, w_ih1, 1024, 16, b_ih1, b_hh1, xg);
    hipMemsetAsync(pub, 0, pub_bytes, stream);
    lstm_scan<<<NSCAN_WG + NHEAT_WG, 512, 0, stream>>>(xg, w_hh1, pub, hseq, done);

    // ---- projection + CRF ----
    proj_kernel<<<M_ROWS / 256, 256, 0, stream>>>((const bf16*)hseq, pw, pb, emis);
    crf_kernel<<<BATCH, 64, 0, stream>>>(emis, tags, mask, trans, startv, endv, outb);
    finalize<<<1, 64, 0, stream>>>(outb, (float*)d_out);
}